// Round 3
// baseline (494.690 us; speedup 1.0000x reference)
//
#include <hip/hip_runtime.h>
#include <hip/hip_bf16.h>

#define TT 4096
#define HH 1024
#define II 768
#define EE 8
#define TWOI 1536

typedef __attribute__((ext_vector_type(8))) short bf16x8;
typedef __attribute__((ext_vector_type(4))) float f32x4;

// static device scratch (avoids any ws_size assumptions)
__device__ unsigned short g_x_bf[TT * HH];            // 8.4 MB
__device__ unsigned short g_w13_bf[EE * TWOI * HH];   // 25.2 MB
__device__ unsigned short g_w2_bf[EE * HH * II];      // 12.6 MB
__device__ unsigned short g_a[EE * TT * II];          // 50.3 MB
__device__ int g_perm_tok[EE * TT];
__device__ float g_perm_w[EE * TT];
__device__ int g_cnt[EE];

__device__ __forceinline__ unsigned short f2bf(float f) {
  union { float f; unsigned u; } v; v.f = f;
  unsigned r = v.u + 0x7fff + ((v.u >> 16) & 1);   // RNE
  return (unsigned short)(r >> 16);
}

__device__ __forceinline__ void gload16(const void* g, void* l) {
  __builtin_amdgcn_global_load_lds(
      (const __attribute__((address_space(1))) void*)g,
      (__attribute__((address_space(3))) void*)l, 16, 0, 0);
}

__global__ void k_zero() {
  if (threadIdx.x < EE) g_cnt[threadIdx.x] = 0;
}

// f32 -> bf16 conversion into static buffers. which: 1 = w13, 2 = w2
__global__ void k_cvt(const float* __restrict__ in, int n, int which) {
  unsigned short* dst = (which == 1) ? g_w13_bf : g_w2_bf;
  int idx = (blockIdx.x * blockDim.x + threadIdx.x) * 4;
  int stride = gridDim.x * blockDim.x * 4;
  for (; idx < n; idx += stride) {
    float4 v = *(const float4*)(in + idx);
    ushort4 o;
    o.x = f2bf(v.x); o.y = f2bf(v.y); o.z = f2bf(v.z); o.w = f2bf(v.w);
    *(ushort4*)(dst + idx) = o;
  }
}

// one wave per token: f32 logits, softmax, top-2 (first-index tie-break),
// scatter into per-expert lists; also emits x in bf16.
__global__ __launch_bounds__(256) void k_router(const float* __restrict__ x,
                                                const float* __restrict__ gw) {
  const int lane = threadIdx.x & 63;
  const int wid = threadIdx.x >> 6;
  const int t = blockIdx.x * 4 + wid;

  const float* xr = x + (size_t)t * HH + lane * 16;
  float4 xv0 = *(const float4*)(xr + 0);
  float4 xv1 = *(const float4*)(xr + 4);
  float4 xv2 = *(const float4*)(xr + 8);
  float4 xv3 = *(const float4*)(xr + 12);

  // emit x as bf16 (coalesced 8B stores)
  unsigned short* xd = g_x_bf + (size_t)t * HH + lane * 16;
  ushort4 o0, o1, o2, o3;
  o0.x = f2bf(xv0.x); o0.y = f2bf(xv0.y); o0.z = f2bf(xv0.z); o0.w = f2bf(xv0.w);
  o1.x = f2bf(xv1.x); o1.y = f2bf(xv1.y); o1.z = f2bf(xv1.z); o1.w = f2bf(xv1.w);
  o2.x = f2bf(xv2.x); o2.y = f2bf(xv2.y); o2.z = f2bf(xv2.z); o2.w = f2bf(xv2.w);
  o3.x = f2bf(xv3.x); o3.y = f2bf(xv3.y); o3.z = f2bf(xv3.z); o3.w = f2bf(xv3.w);
  *(ushort4*)(xd + 0) = o0;
  *(ushort4*)(xd + 4) = o1;
  *(ushort4*)(xd + 8) = o2;
  *(ushort4*)(xd + 12) = o3;

  float lg[EE];
#pragma unroll
  for (int ei = 0; ei < EE; ++ei) {
    const float* gr = gw + ei * HH + lane * 16;
    float4 g0 = *(const float4*)(gr + 0);
    float4 g1 = *(const float4*)(gr + 4);
    float4 g2 = *(const float4*)(gr + 8);
    float4 g3 = *(const float4*)(gr + 12);
    float a = xv0.x * g0.x + xv0.y * g0.y + xv0.z * g0.z + xv0.w * g0.w
            + xv1.x * g1.x + xv1.y * g1.y + xv1.z * g1.z + xv1.w * g1.w
            + xv2.x * g2.x + xv2.y * g2.y + xv2.z * g2.z + xv2.w * g2.w
            + xv3.x * g3.x + xv3.y * g3.y + xv3.z * g3.z + xv3.w * g3.w;
#pragma unroll
    for (int s = 32; s > 0; s >>= 1) a += __shfl_xor(a, s);
    lg[ei] = a;
  }

  if (lane == 0) {
    float mx = lg[0];
#pragma unroll
    for (int ei = 1; ei < EE; ++ei) mx = fmaxf(mx, lg[ei]);
    float p[EE]; float s = 0.f;
#pragma unroll
    for (int ei = 0; ei < EE; ++ei) { p[ei] = expf(lg[ei] - mx); s += p[ei]; }
    float inv = 1.f / s;
    int e1 = 0; float b1 = lg[0];
#pragma unroll
    for (int ei = 1; ei < EE; ++ei) if (lg[ei] > b1) { b1 = lg[ei]; e1 = ei; }
    int e2 = -1; float b2 = -3.0e38f;
#pragma unroll
    for (int ei = 0; ei < EE; ++ei)
      if (ei != e1 && lg[ei] > b2) { b2 = lg[ei]; e2 = ei; }

    int p1 = atomicAdd(&g_cnt[e1], 1);
    g_perm_tok[e1 * TT + p1] = t;
    g_perm_w[e1 * TT + p1] = p[e1] * inv;
    int p2 = atomicAdd(&g_cnt[e2], 1);
    g_perm_tok[e2 * TT + p2] = t;
    g_perm_w[e2 * TT + p2] = p[e2] * inv;
  }
}

// GEMM1: for expert e, rows = gathered tokens, cols = i in [cb*128, cb*128+128),
// computes gate (j=i) and up (j=i+768) halves, fused silu, a -> bf16.
// Fragment-ordered LDS: chunk c (1KB) holds a 16(row)x32(k) fragment,
// granule within chunk = (k8)*16 + r16, so reads are lane-contiguous.
__global__ __launch_bounds__(256) void k_gemm1() {
  const int e = blockIdx.z;
  const int cnt = g_cnt[e];
  const int rowbase = blockIdx.x * 128;
  if (rowbase >= cnt) return;
  const int cb = blockIdx.y;          // 0..5
  const int tid = threadIdx.x;
  const int lane = tid & 63;
  const int wid = tid >> 6;
  const int wm = wid >> 1, wn = wid & 1;

  __shared__ uint4 sA[512];   // 8KB: 8 chunks of (16 rows x 32 k)
  __shared__ uint4 sBg[512];
  __shared__ uint4 sBu[512];

  const unsigned short* xb = g_x_bf;
  const unsigned short* w13b = g_w13_bf + (size_t)e * TWOI * HH;

  const unsigned short* aptr[2];
  const unsigned short* bgptr[2];
  const unsigned short* buptr[2];
#pragma unroll
  for (int is = 0; is < 2; ++is) {
    int g = is * 256 + tid;
    int rb = g >> 6;
    int c8 = (g >> 4) & 3;
    int r16 = g & 15;
    int r = rb * 16 + r16;
    int row = rowbase + r;
    int tok = (row < cnt) ? g_perm_tok[e * TT + row] : 0;
    aptr[is] = xb + (size_t)tok * HH + c8 * 8;
    int j = cb * 128 + r;
    bgptr[is] = w13b + (size_t)j * HH + c8 * 8;
    buptr[is] = w13b + (size_t)(j + II) * HH + c8 * 8;
  }

  f32x4 accg[4][4];
  f32x4 accu[4][4];
#pragma unroll
  for (int m = 0; m < 4; ++m)
#pragma unroll
    for (int n = 0; n < 4; ++n) {
      accg[m][n] = (f32x4){0.f, 0.f, 0.f, 0.f};
      accu[m][n] = (f32x4){0.f, 0.f, 0.f, 0.f};
    }

  for (int k0 = 0; k0 < HH; k0 += 32) {
    __syncthreads();
#pragma unroll
    for (int is = 0; is < 2; ++is) {
      int ldsg = is * 256 + wid * 64;   // granule index, wave-uniform base
      gload16(aptr[is] + k0, (char*)sA + ldsg * 16);
      gload16(bgptr[is] + k0, (char*)sBg + ldsg * 16);
      gload16(buptr[is] + k0, (char*)sBu + ldsg * 16);
    }
    __syncthreads();
    bf16x8 af[4], bg[4], bu[4];
#pragma unroll
    for (int m = 0; m < 4; ++m) {
      int rb = wm * 4 + m;
      af[m] = *(const bf16x8*)((const char*)sA + rb * 1024 + lane * 16);
    }
#pragma unroll
    for (int n = 0; n < 4; ++n) {
      int jb = wn * 4 + n;
      bg[n] = *(const bf16x8*)((const char*)sBg + jb * 1024 + lane * 16);
      bu[n] = *(const bf16x8*)((const char*)sBu + jb * 1024 + lane * 16);
    }
#pragma unroll
    for (int m = 0; m < 4; ++m)
#pragma unroll
      for (int n = 0; n < 4; ++n) {
        accg[m][n] = __builtin_amdgcn_mfma_f32_16x16x32_bf16(af[m], bg[n], accg[m][n], 0, 0, 0);
        accu[m][n] = __builtin_amdgcn_mfma_f32_16x16x32_bf16(af[m], bu[n], accu[m][n], 0, 0, 0);
      }
  }

  const int rhi = lane >> 4, clo = lane & 15;
#pragma unroll
  for (int m = 0; m < 4; ++m) {
#pragma unroll
    for (int j = 0; j < 4; ++j) {
      int rloc = wm * 64 + m * 16 + rhi * 4 + j;
      int row = rowbase + rloc;
      if (row < cnt) {
        unsigned short* arow = g_a + ((size_t)e * TT + row) * II;
#pragma unroll
        for (int n = 0; n < 4; ++n) {
          int i = cb * 128 + wn * 64 + n * 16 + clo;
          float gv = accg[m][n][j];
          float uv = accu[m][n][j];
          float av = gv / (1.f + __expf(-gv)) * uv;
          arow[i] = f2bf(av);
        }
      }
    }
  }
}

// GEMM2: o = a @ w2[e]^T, epilogue scatters weight*o into out via atomicAdd.
__global__ __launch_bounds__(256) void k_gemm2(float* __restrict__ out) {
  const int e = blockIdx.z;
  const int cnt = g_cnt[e];
  const int rowbase = blockIdx.x * 128;
  if (rowbase >= cnt) return;
  const int cb = blockIdx.y;          // 0..7
  const int tid = threadIdx.x;
  const int lane = tid & 63;
  const int wid = tid >> 6;
  const int wm = wid >> 1, wn = wid & 1;

  __shared__ uint4 sA[512];
  __shared__ uint4 sB[512];
  __shared__ int s_tok[128];
  __shared__ float s_w[128];

  if (tid < 128) {
    int row = rowbase + tid;
    bool v = row < cnt;
    s_tok[tid] = v ? g_perm_tok[e * TT + row] : 0;
    s_w[tid] = v ? g_perm_w[e * TT + row] : 0.f;
  }

  const unsigned short* ab = g_a + (size_t)e * TT * II;
  const unsigned short* w2b = g_w2_bf + (size_t)e * HH * II;

  const unsigned short* aptr[2];
  const unsigned short* bptr[2];
#pragma unroll
  for (int is = 0; is < 2; ++is) {
    int g = is * 256 + tid;
    int rb = g >> 6;
    int c8 = (g >> 4) & 3;
    int r16 = g & 15;
    int r = rb * 16 + r16;
    aptr[is] = ab + (size_t)(rowbase + r) * II + c8 * 8;
    int h = cb * 128 + r;
    bptr[is] = w2b + (size_t)h * II + c8 * 8;
  }

  f32x4 acc[4][4];
#pragma unroll
  for (int m = 0; m < 4; ++m)
#pragma unroll
    for (int n = 0; n < 4; ++n) acc[m][n] = (f32x4){0.f, 0.f, 0.f, 0.f};

  for (int k0 = 0; k0 < II; k0 += 32) {
    __syncthreads();
#pragma unroll
    for (int is = 0; is < 2; ++is) {
      int ldsg = is * 256 + wid * 64;
      gload16(aptr[is] + k0, (char*)sA + ldsg * 16);
      gload16(bptr[is] + k0, (char*)sB + ldsg * 16);
    }
    __syncthreads();
    bf16x8 af[4], bfr[4];
#pragma unroll
    for (int m = 0; m < 4; ++m) {
      int rb = wm * 4 + m;
      af[m] = *(const bf16x8*)((const char*)sA + rb * 1024 + lane * 16);
    }
#pragma unroll
    for (int n = 0; n < 4; ++n) {
      int hb = wn * 4 + n;
      bfr[n] = *(const bf16x8*)((const char*)sB + hb * 1024 + lane * 16);
    }
#pragma unroll
    for (int m = 0; m < 4; ++m)
#pragma unroll
      for (int n = 0; n < 4; ++n)
        acc[m][n] = __builtin_amdgcn_mfma_f32_16x16x32_bf16(af[m], bfr[n], acc[m][n], 0, 0, 0);
  }

  const int rhi = lane >> 4, clo = lane & 15;
#pragma unroll
  for (int m = 0; m < 4; ++m) {
#pragma unroll
    for (int j = 0; j < 4; ++j) {
      int rloc = wm * 64 + m * 16 + rhi * 4 + j;
      if (rowbase + rloc < cnt) {
        int tok = s_tok[rloc];
        float w = s_w[rloc];
        float* orow = out + (size_t)tok * HH;
#pragma unroll
        for (int n = 0; n < 4; ++n) {
          int h = cb * 128 + wn * 64 + n * 16 + clo;
          atomicAdd(orow + h, w * acc[m][n][j]);
        }
      }
    }
  }
}

extern "C" void kernel_launch(void* const* d_in, const int* in_sizes, int n_in,
                              void* d_out, int out_size, void* d_ws, size_t ws_size,
                              hipStream_t stream) {
  (void)in_sizes; (void)n_in; (void)d_ws; (void)ws_size; (void)out_size;
  const float* x   = (const float*)d_in[0];
  const float* gw  = (const float*)d_in[1];
  const float* w13 = (const float*)d_in[2];
  const float* w2  = (const float*)d_in[3];
  float* out = (float*)d_out;

  k_zero<<<dim3(1), dim3(64), 0, stream>>>();
  k_cvt<<<dim3(2048), dim3(256), 0, stream>>>(w13, EE * TWOI * HH, 1);
  k_cvt<<<dim3(2048), dim3(256), 0, stream>>>(w2, EE * HH * II, 2);
  k_router<<<dim3(TT / 4), dim3(256), 0, stream>>>(x, gw);
  hipMemsetAsync(d_out, 0, (size_t)TT * HH * sizeof(float), stream);
  k_gemm1<<<dim3(32, 6, EE), dim3(256), 0, stream>>>();
  k_gemm2<<<dim3(32, 8, EE), dim3(256), 0, stream>>>(out);
}

// Round 4
// 309.203 us; speedup vs baseline: 1.5999x; 1.5999x over previous
//
#include <hip/hip_runtime.h>
#include <hip/hip_bf16.h>

#define TT 4096
#define HH 1024
#define II 768
#define EE 8
#define TWOI 1536

typedef __attribute__((ext_vector_type(8))) short bf16x8;
typedef __attribute__((ext_vector_type(4))) float f32x4;

// static device scratch
__device__ unsigned short g_x_bf[TT * HH];
__device__ unsigned short g_w13_bf[EE * TWOI * HH];
__device__ unsigned short g_w2_bf[EE * HH * II];
__device__ unsigned short g_a[EE * TT * II];
__device__ int g_perm_tok[EE * TT];
__device__ float g_perm_w[EE * TT];
__device__ int g_cnt[EE];

__device__ __forceinline__ unsigned short f2bf(float f) {
  union { float f; unsigned u; } v; v.f = f;
  unsigned r = v.u + 0x7fff + ((v.u >> 16) & 1);   // RNE
  return (unsigned short)(r >> 16);
}

__device__ __forceinline__ void gload16(const void* g, void* l) {
  __builtin_amdgcn_global_load_lds(
      (const __attribute__((address_space(1))) void*)g,
      (__attribute__((address_space(3))) void*)l, 16, 0, 0);
}

__global__ void k_zero() {
  if (threadIdx.x < EE) g_cnt[threadIdx.x] = 0;
}

__global__ void k_cvt(const float* __restrict__ in, int n, int which) {
  unsigned short* dst = (which == 1) ? g_w13_bf : g_w2_bf;
  int idx = (blockIdx.x * blockDim.x + threadIdx.x) * 4;
  int stride = gridDim.x * blockDim.x * 4;
  for (; idx < n; idx += stride) {
    float4 v = *(const float4*)(in + idx);
    ushort4 o;
    o.x = f2bf(v.x); o.y = f2bf(v.y); o.z = f2bf(v.z); o.w = f2bf(v.w);
    *(ushort4*)(dst + idx) = o;
  }
}

// one wave per token: f32 logits, softmax, top-2; scatter to expert lists; x->bf16
__global__ __launch_bounds__(256) void k_router(const float* __restrict__ x,
                                                const float* __restrict__ gw) {
  const int lane = threadIdx.x & 63;
  const int wid = threadIdx.x >> 6;
  const int t = blockIdx.x * 4 + wid;

  const float* xr = x + (size_t)t * HH + lane * 16;
  float4 xv0 = *(const float4*)(xr + 0);
  float4 xv1 = *(const float4*)(xr + 4);
  float4 xv2 = *(const float4*)(xr + 8);
  float4 xv3 = *(const float4*)(xr + 12);

  unsigned short* xd = g_x_bf + (size_t)t * HH + lane * 16;
  ushort4 o0, o1, o2, o3;
  o0.x = f2bf(xv0.x); o0.y = f2bf(xv0.y); o0.z = f2bf(xv0.z); o0.w = f2bf(xv0.w);
  o1.x = f2bf(xv1.x); o1.y = f2bf(xv1.y); o1.z = f2bf(xv1.z); o1.w = f2bf(xv1.w);
  o2.x = f2bf(xv2.x); o2.y = f2bf(xv2.y); o2.z = f2bf(xv2.z); o2.w = f2bf(xv2.w);
  o3.x = f2bf(xv3.x); o3.y = f2bf(xv3.y); o3.z = f2bf(xv3.z); o3.w = f2bf(xv3.w);
  *(ushort4*)(xd + 0) = o0;
  *(ushort4*)(xd + 4) = o1;
  *(ushort4*)(xd + 8) = o2;
  *(ushort4*)(xd + 12) = o3;

  float lg[EE];
#pragma unroll
  for (int ei = 0; ei < EE; ++ei) {
    const float* gr = gw + ei * HH + lane * 16;
    float4 g0 = *(const float4*)(gr + 0);
    float4 g1 = *(const float4*)(gr + 4);
    float4 g2 = *(const float4*)(gr + 8);
    float4 g3 = *(const float4*)(gr + 12);
    float a = xv0.x * g0.x + xv0.y * g0.y + xv0.z * g0.z + xv0.w * g0.w
            + xv1.x * g1.x + xv1.y * g1.y + xv1.z * g1.z + xv1.w * g1.w
            + xv2.x * g2.x + xv2.y * g2.y + xv2.z * g2.z + xv2.w * g2.w
            + xv3.x * g3.x + xv3.y * g3.y + xv3.z * g3.z + xv3.w * g3.w;
#pragma unroll
    for (int s = 32; s > 0; s >>= 1) a += __shfl_xor(a, s);
    lg[ei] = a;
  }

  if (lane == 0) {
    float mx = lg[0];
#pragma unroll
    for (int ei = 1; ei < EE; ++ei) mx = fmaxf(mx, lg[ei]);
    float p[EE]; float s = 0.f;
#pragma unroll
    for (int ei = 0; ei < EE; ++ei) { p[ei] = expf(lg[ei] - mx); s += p[ei]; }
    float inv = 1.f / s;
    int e1 = 0; float b1 = lg[0];
#pragma unroll
    for (int ei = 1; ei < EE; ++ei) if (lg[ei] > b1) { b1 = lg[ei]; e1 = ei; }
    int e2 = -1; float b2 = -3.0e38f;
#pragma unroll
    for (int ei = 0; ei < EE; ++ei)
      if (ei != e1 && lg[ei] > b2) { b2 = lg[ei]; e2 = ei; }

    int p1 = atomicAdd(&g_cnt[e1], 1);
    g_perm_tok[e1 * TT + p1] = t;
    g_perm_w[e1 * TT + p1] = p[e1] * inv;
    int p2 = atomicAdd(&g_cnt[e2], 1);
    g_perm_tok[e2 * TT + p2] = t;
    g_perm_w[e2 * TT + p2] = p[e2] * inv;
  }
}

// GEMM1: 64-row x 128-icol tile, g+u, double-buffered LDS, counted vmcnt.
// Fragment-ordered LDS: 1KB chunk = 16(row)x32(k) fragment, granule = c8*16+r16.
__global__ __launch_bounds__(256) void k_gemm1() {
  const int e = blockIdx.z;
  const int cnt = g_cnt[e];
  const int rowbase = blockIdx.x * 64;
  if (rowbase >= cnt) return;
  const int cb = blockIdx.y;          // 0..5
  const int tid = threadIdx.x;
  const int lane = tid & 63;
  const int wid = tid >> 6;
  const int wm = wid >> 1;            // row half (32 rows)
  const int wc = wid & 1;             // col half (64 cols)

  __shared__ uint4 sA[2][256];        // 4KB per buf
  __shared__ uint4 sBg[2][512];       // 8KB per buf
  __shared__ uint4 sBu[2][512];       // 8KB per buf

  const int r16 = tid & 15;
  const int c8 = (tid >> 4) & 3;
  const int arow = rowbase + ((tid >> 6) << 4) + r16;
  const int tok = (arow < cnt) ? g_perm_tok[e * TT + arow] : 0;
  const unsigned short* aptr = g_x_bf + (size_t)tok * HH + c8 * 8;
  const unsigned short* w13b = g_w13_bf + (size_t)e * TWOI * HH;
  const int j0 = cb * 128 + ((tid >> 6) << 4) + r16;        // chunks 0..3
  const int j1 = cb * 128 + (4 + (tid >> 6)) * 16 + r16;    // chunks 4..7
  const unsigned short* bgp0 = w13b + (size_t)j0 * HH + c8 * 8;
  const unsigned short* bgp1 = w13b + (size_t)j1 * HH + c8 * 8;
  const unsigned short* bup0 = bgp0 + (size_t)II * HH;
  const unsigned short* bup1 = bgp1 + (size_t)II * HH;

  const int aoff  = __builtin_amdgcn_readfirstlane(wid * 64 * 16);
  const int boff1 = __builtin_amdgcn_readfirstlane((256 + wid * 64) * 16);

#define STG1(buf, kk) do { \
    gload16(aptr + (kk), (char*)(&sA[buf][0]) + aoff); \
    gload16(bgp0 + (kk), (char*)(&sBg[buf][0]) + aoff); \
    gload16(bgp1 + (kk), (char*)(&sBg[buf][0]) + boff1); \
    gload16(bup0 + (kk), (char*)(&sBu[buf][0]) + aoff); \
    gload16(bup1 + (kk), (char*)(&sBu[buf][0]) + boff1); \
  } while (0)

  f32x4 accg[2][4], accu[2][4];
#pragma unroll
  for (int m = 0; m < 2; ++m)
#pragma unroll
    for (int n = 0; n < 4; ++n) {
      accg[m][n] = (f32x4){0.f, 0.f, 0.f, 0.f};
      accu[m][n] = (f32x4){0.f, 0.f, 0.f, 0.f};
    }

  STG1(0, 0);
  for (int ks = 0; ks < 32; ++ks) {
    const int cur = ks & 1;
    if (ks < 31) {
      STG1(cur ^ 1, (ks + 1) * 32);
      asm volatile("s_waitcnt vmcnt(5)" ::: "memory");
    } else {
      asm volatile("s_waitcnt vmcnt(0)" ::: "memory");
    }
    __builtin_amdgcn_s_barrier();
    __builtin_amdgcn_sched_barrier(0);
    bf16x8 af[2], bgf[4], buf_[4];
#pragma unroll
    for (int m = 0; m < 2; ++m)
      af[m] = *(const bf16x8*)((const char*)(&sA[cur][0]) + (wm * 2 + m) * 1024 + lane * 16);
#pragma unroll
    for (int n = 0; n < 4; ++n) {
      int jb = wc * 4 + n;
      bgf[n] = *(const bf16x8*)((const char*)(&sBg[cur][0]) + jb * 1024 + lane * 16);
      buf_[n] = *(const bf16x8*)((const char*)(&sBu[cur][0]) + jb * 1024 + lane * 16);
    }
#pragma unroll
    for (int m = 0; m < 2; ++m)
#pragma unroll
      for (int n = 0; n < 4; ++n) {
        accg[m][n] = __builtin_amdgcn_mfma_f32_16x16x32_bf16(af[m], bgf[n], accg[m][n], 0, 0, 0);
        accu[m][n] = __builtin_amdgcn_mfma_f32_16x16x32_bf16(af[m], buf_[n], accu[m][n], 0, 0, 0);
      }
    __builtin_amdgcn_sched_barrier(0);
    __builtin_amdgcn_s_barrier();
  }
#undef STG1

  const int rhi = lane >> 4, clo = lane & 15;
#pragma unroll
  for (int m = 0; m < 2; ++m) {
#pragma unroll
    for (int jj = 0; jj < 4; ++jj) {
      int rloc = wm * 32 + m * 16 + rhi * 4 + jj;
      int row = rowbase + rloc;
      if (row < cnt) {
        unsigned short* ar = g_a + ((size_t)e * TT + row) * II;
#pragma unroll
        for (int n = 0; n < 4; ++n) {
          int i = cb * 128 + wc * 64 + n * 16 + clo;
          float gv = accg[m][n][jj];
          float uv = accu[m][n][jj];
          float av = gv / (1.f + __expf(-gv)) * uv;
          ar[i] = f2bf(av);
        }
      }
    }
  }
}

// GEMM2: 64-row x 128-hcol tile, K=768, double-buffered; atomicAdd combine.
__global__ __launch_bounds__(256) void k_gemm2(float* __restrict__ out) {
  const int e = blockIdx.z;
  const int cnt = g_cnt[e];
  const int rowbase = blockIdx.x * 64;
  if (rowbase >= cnt) return;
  const int cb = blockIdx.y;          // 0..7
  const int tid = threadIdx.x;
  const int lane = tid & 63;
  const int wid = tid >> 6;
  const int wm = wid >> 1;
  const int wc = wid & 1;

  __shared__ uint4 sA[2][256];
  __shared__ uint4 sB[2][512];
  __shared__ int s_tok[64];
  __shared__ float s_w[64];

  if (tid < 64) {
    int row = rowbase + tid;
    bool v = row < cnt;
    s_tok[tid] = v ? g_perm_tok[e * TT + row] : 0;
    s_w[tid] = v ? g_perm_w[e * TT + row] : 0.f;
  }

  const int r16 = tid & 15;
  const int c8 = (tid >> 4) & 3;
  const unsigned short* ab = g_a + (size_t)e * TT * II;
  const unsigned short* aptr = ab + (size_t)(rowbase + ((tid >> 6) << 4) + r16) * II + c8 * 8;
  const unsigned short* w2b = g_w2_bf + (size_t)e * HH * II;
  const int h0 = cb * 128 + ((tid >> 6) << 4) + r16;
  const int h1 = cb * 128 + (4 + (tid >> 6)) * 16 + r16;
  const unsigned short* bp0 = w2b + (size_t)h0 * II + c8 * 8;
  const unsigned short* bp1 = w2b + (size_t)h1 * II + c8 * 8;

  const int aoff  = __builtin_amdgcn_readfirstlane(wid * 64 * 16);
  const int boff1 = __builtin_amdgcn_readfirstlane((256 + wid * 64) * 16);

#define STG2(buf, kk) do { \
    gload16(aptr + (kk), (char*)(&sA[buf][0]) + aoff); \
    gload16(bp0 + (kk), (char*)(&sB[buf][0]) + aoff); \
    gload16(bp1 + (kk), (char*)(&sB[buf][0]) + boff1); \
  } while (0)

  f32x4 acc[2][4];
#pragma unroll
  for (int m = 0; m < 2; ++m)
#pragma unroll
    for (int n = 0; n < 4; ++n) acc[m][n] = (f32x4){0.f, 0.f, 0.f, 0.f};

  STG2(0, 0);
  for (int ks = 0; ks < 24; ++ks) {
    const int cur = ks & 1;
    if (ks < 23) {
      STG2(cur ^ 1, (ks + 1) * 32);
      asm volatile("s_waitcnt vmcnt(3)" ::: "memory");
    } else {
      asm volatile("s_waitcnt vmcnt(0)" ::: "memory");
    }
    __builtin_amdgcn_s_barrier();
    __builtin_amdgcn_sched_barrier(0);
    bf16x8 af[2], bfr[4];
#pragma unroll
    for (int m = 0; m < 2; ++m)
      af[m] = *(const bf16x8*)((const char*)(&sA[cur][0]) + (wm * 2 + m) * 1024 + lane * 16);
#pragma unroll
    for (int n = 0; n < 4; ++n)
      bfr[n] = *(const bf16x8*)((const char*)(&sB[cur][0]) + (wc * 4 + n) * 1024 + lane * 16);
#pragma unroll
    for (int m = 0; m < 2; ++m)
#pragma unroll
      for (int n = 0; n < 4; ++n)
        acc[m][n] = __builtin_amdgcn_mfma_f32_16x16x32_bf16(af[m], bfr[n], acc[m][n], 0, 0, 0);
    __builtin_amdgcn_sched_barrier(0);
    __builtin_amdgcn_s_barrier();
  }
#undef STG2

  const int rhi = lane >> 4, clo = lane & 15;
#pragma unroll
  for (int m = 0; m < 2; ++m) {
#pragma unroll
    for (int jj = 0; jj < 4; ++jj) {
      int rloc = wm * 32 + m * 16 + rhi * 4 + jj;
      if (rowbase + rloc < cnt) {
        int tok = s_tok[rloc];
        float w = s_w[rloc];
        float* orow = out + (size_t)tok * HH;
#pragma unroll
        for (int n = 0; n < 4; ++n) {
          int h = cb * 128 + wc * 64 + n * 16 + clo;
          atomicAdd(orow + h, w * acc[m][n][jj]);
        }
      }
    }
  }
}

extern "C" void kernel_launch(void* const* d_in, const int* in_sizes, int n_in,
                              void* d_out, int out_size, void* d_ws, size_t ws_size,
                              hipStream_t stream) {
  (void)in_sizes; (void)n_in; (void)d_ws; (void)ws_size; (void)out_size;
  const float* x   = (const float*)d_in[0];
  const float* gw  = (const float*)d_in[1];
  const float* w13 = (const float*)d_in[2];
  const float* w2  = (const float*)d_in[3];
  float* out = (float*)d_out;

  k_zero<<<dim3(1), dim3(64), 0, stream>>>();
  k_cvt<<<dim3(2048), dim3(256), 0, stream>>>(w13, EE * TWOI * HH, 1);
  k_cvt<<<dim3(2048), dim3(256), 0, stream>>>(w2, EE * HH * II, 2);
  k_router<<<dim3(TT / 4), dim3(256), 0, stream>>>(x, gw);
  hipMemsetAsync(d_out, 0, (size_t)TT * HH * sizeof(float), stream);
  k_gemm1<<<dim3(64, 6, EE), dim3(256), 0, stream>>>();
  k_gemm2<<<dim3(64, 8, EE), dim3(256), 0, stream>>>(out);
}

// Round 5
// 252.012 us; speedup vs baseline: 1.9630x; 1.2269x over previous
//
#include <hip/hip_runtime.h>
#include <hip/hip_bf16.h>

#define TT 4096
#define HH 1024
#define II 768
#define EE 8
#define TWOI 1536
#define MAXTILES 136

typedef __attribute__((ext_vector_type(8))) short bf16x8;
typedef __attribute__((ext_vector_type(4))) float f32x4;

// static device scratch
__device__ unsigned short g_x_bf[TT * HH];
__device__ unsigned short g_w13_bf[EE * TWOI * HH];
__device__ unsigned short g_w2_bf[EE * HH * II];
__device__ unsigned short g_a[EE * TT * II];
__device__ int g_perm_tok[EE * TT];
__device__ float g_perm_w[EE * TT];
__device__ int g_cnt[EE];
__device__ int g_tile_e[MAXTILES];
__device__ int g_tile_row[MAXTILES];
__device__ int g_ntiles;

__device__ __forceinline__ unsigned short f2bf(float f) {
  union { float f; unsigned u; } v; v.f = f;
  unsigned r = v.u + 0x7fff + ((v.u >> 16) & 1);   // RNE
  return (unsigned short)(r >> 16);
}

__device__ __forceinline__ void gload16(const void* g, void* l) {
  __builtin_amdgcn_global_load_lds(
      (const __attribute__((address_space(1))) void*)g,
      (__attribute__((address_space(3))) void*)l, 16, 0, 0);
}

__global__ void k_zero() {
  if (threadIdx.x < EE) g_cnt[threadIdx.x] = 0;
}

__global__ void k_cvt(const float* __restrict__ in, int n, int which) {
  unsigned short* dst = (which == 1) ? g_w13_bf : g_w2_bf;
  int idx = (blockIdx.x * blockDim.x + threadIdx.x) * 4;
  int stride = gridDim.x * blockDim.x * 4;
  for (; idx < n; idx += stride) {
    float4 v = *(const float4*)(in + idx);
    ushort4 o;
    o.x = f2bf(v.x); o.y = f2bf(v.y); o.z = f2bf(v.z); o.w = f2bf(v.w);
    *(ushort4*)(dst + idx) = o;
  }
}

// one wave per token: f32 logits, softmax, top-2; scatter to expert lists; x->bf16
__global__ __launch_bounds__(256) void k_router(const float* __restrict__ x,
                                                const float* __restrict__ gw) {
  const int lane = threadIdx.x & 63;
  const int wid = threadIdx.x >> 6;
  const int t = blockIdx.x * 4 + wid;

  const float* xr = x + (size_t)t * HH + lane * 16;
  float4 xv0 = *(const float4*)(xr + 0);
  float4 xv1 = *(const float4*)(xr + 4);
  float4 xv2 = *(const float4*)(xr + 8);
  float4 xv3 = *(const float4*)(xr + 12);

  unsigned short* xd = g_x_bf + (size_t)t * HH + lane * 16;
  ushort4 o0, o1, o2, o3;
  o0.x = f2bf(xv0.x); o0.y = f2bf(xv0.y); o0.z = f2bf(xv0.z); o0.w = f2bf(xv0.w);
  o1.x = f2bf(xv1.x); o1.y = f2bf(xv1.y); o1.z = f2bf(xv1.z); o1.w = f2bf(xv1.w);
  o2.x = f2bf(xv2.x); o2.y = f2bf(xv2.y); o2.z = f2bf(xv2.z); o2.w = f2bf(xv2.w);
  o3.x = f2bf(xv3.x); o3.y = f2bf(xv3.y); o3.z = f2bf(xv3.z); o3.w = f2bf(xv3.w);
  *(ushort4*)(xd + 0) = o0;
  *(ushort4*)(xd + 4) = o1;
  *(ushort4*)(xd + 8) = o2;
  *(ushort4*)(xd + 12) = o3;

  float lg[EE];
#pragma unroll
  for (int ei = 0; ei < EE; ++ei) {
    const float* gr = gw + ei * HH + lane * 16;
    float4 g0 = *(const float4*)(gr + 0);
    float4 g1 = *(const float4*)(gr + 4);
    float4 g2 = *(const float4*)(gr + 8);
    float4 g3 = *(const float4*)(gr + 12);
    float a = xv0.x * g0.x + xv0.y * g0.y + xv0.z * g0.z + xv0.w * g0.w
            + xv1.x * g1.x + xv1.y * g1.y + xv1.z * g1.z + xv1.w * g1.w
            + xv2.x * g2.x + xv2.y * g2.y + xv2.z * g2.z + xv2.w * g2.w
            + xv3.x * g3.x + xv3.y * g3.y + xv3.z * g3.z + xv3.w * g3.w;
#pragma unroll
    for (int s = 32; s > 0; s >>= 1) a += __shfl_xor(a, s);
    lg[ei] = a;
  }

  if (lane == 0) {
    float mx = lg[0];
#pragma unroll
    for (int ei = 1; ei < EE; ++ei) mx = fmaxf(mx, lg[ei]);
    float p[EE]; float s = 0.f;
#pragma unroll
    for (int ei = 0; ei < EE; ++ei) { p[ei] = expf(lg[ei] - mx); s += p[ei]; }
    float inv = 1.f / s;
    int e1 = 0; float b1 = lg[0];
#pragma unroll
    for (int ei = 1; ei < EE; ++ei) if (lg[ei] > b1) { b1 = lg[ei]; e1 = ei; }
    int e2 = -1; float b2 = -3.0e38f;
#pragma unroll
    for (int ei = 0; ei < EE; ++ei)
      if (ei != e1 && lg[ei] > b2) { b2 = lg[ei]; e2 = ei; }

    int p1 = atomicAdd(&g_cnt[e1], 1);
    g_perm_tok[e1 * TT + p1] = t;
    g_perm_w[e1 * TT + p1] = p[e1] * inv;
    int p2 = atomicAdd(&g_cnt[e2], 1);
    g_perm_tok[e2 * TT + p2] = t;
    g_perm_w[e2 * TT + p2] = p[e2] * inv;
  }
}

// build compact tile list: tile -> (expert, rowbase), 64-row tiles
__global__ void k_prefix() {
  if (threadIdx.x == 0) {
    int t = 0;
    for (int e = 0; e < EE; ++e) {
      int c = g_cnt[e];
      for (int rb = 0; rb < c; rb += 64) {
        g_tile_e[t] = e;
        g_tile_row[t] = rb;
        ++t;
      }
    }
    g_ntiles = t;
  }
}

// GEMM1: 64-row x 128-icol tile, g+u, double-buffered LDS, counted vmcnt.
// Fragment-ordered LDS: 1KB chunk = 16(row)x32(k) fragment, granule = c8*16+r16.
__global__ __launch_bounds__(256) void k_gemm1() {
  const int tile = blockIdx.x;
  if (tile >= g_ntiles) return;
  const int e = g_tile_e[tile];
  const int rowbase = g_tile_row[tile];
  const int cnt = g_cnt[e];
  const int cb = blockIdx.y;          // 0..5
  const int tid = threadIdx.x;
  const int lane = tid & 63;
  const int wid = tid >> 6;
  const int wm = wid >> 1;            // row half (32 rows)
  const int wc = wid & 1;             // col half (64 cols)

  __shared__ uint4 sA[2][256];        // 4KB per buf
  __shared__ uint4 sBg[2][512];       // 8KB per buf
  __shared__ uint4 sBu[2][512];       // 8KB per buf

  const int r16 = tid & 15;
  const int c8 = (tid >> 4) & 3;
  const int arow = rowbase + ((tid >> 6) << 4) + r16;
  const int tok = (arow < cnt) ? g_perm_tok[e * TT + arow] : 0;
  const unsigned short* aptr = g_x_bf + (size_t)tok * HH + c8 * 8;
  const unsigned short* w13b = g_w13_bf + (size_t)e * TWOI * HH;
  const int j0 = cb * 128 + ((tid >> 6) << 4) + r16;        // chunks 0..3
  const int j1 = cb * 128 + (4 + (tid >> 6)) * 16 + r16;    // chunks 4..7
  const unsigned short* bgp0 = w13b + (size_t)j0 * HH + c8 * 8;
  const unsigned short* bgp1 = w13b + (size_t)j1 * HH + c8 * 8;
  const unsigned short* bup0 = bgp0 + (size_t)II * HH;
  const unsigned short* bup1 = bgp1 + (size_t)II * HH;

  const int aoff  = __builtin_amdgcn_readfirstlane(wid * 64 * 16);
  const int boff1 = __builtin_amdgcn_readfirstlane((256 + wid * 64) * 16);

#define STG1(buf, kk) do { \
    gload16(aptr + (kk), (char*)(&sA[buf][0]) + aoff); \
    gload16(bgp0 + (kk), (char*)(&sBg[buf][0]) + aoff); \
    gload16(bgp1 + (kk), (char*)(&sBg[buf][0]) + boff1); \
    gload16(bup0 + (kk), (char*)(&sBu[buf][0]) + aoff); \
    gload16(bup1 + (kk), (char*)(&sBu[buf][0]) + boff1); \
  } while (0)

  f32x4 accg[2][4], accu[2][4];
#pragma unroll
  for (int m = 0; m < 2; ++m)
#pragma unroll
    for (int n = 0; n < 4; ++n) {
      accg[m][n] = (f32x4){0.f, 0.f, 0.f, 0.f};
      accu[m][n] = (f32x4){0.f, 0.f, 0.f, 0.f};
    }

  STG1(0, 0);
  for (int ks = 0; ks < 32; ++ks) {
    const int cur = ks & 1;
    if (ks < 31) {
      STG1(cur ^ 1, (ks + 1) * 32);
      asm volatile("s_waitcnt vmcnt(5)" ::: "memory");
    } else {
      asm volatile("s_waitcnt vmcnt(0)" ::: "memory");
    }
    __builtin_amdgcn_s_barrier();
    __builtin_amdgcn_sched_barrier(0);
    bf16x8 af[2], bgf[4], buf_[4];
#pragma unroll
    for (int m = 0; m < 2; ++m)
      af[m] = *(const bf16x8*)((const char*)(&sA[cur][0]) + (wm * 2 + m) * 1024 + lane * 16);
#pragma unroll
    for (int n = 0; n < 4; ++n) {
      int jb = wc * 4 + n;
      bgf[n] = *(const bf16x8*)((const char*)(&sBg[cur][0]) + jb * 1024 + lane * 16);
      buf_[n] = *(const bf16x8*)((const char*)(&sBu[cur][0]) + jb * 1024 + lane * 16);
    }
#pragma unroll
    for (int m = 0; m < 2; ++m)
#pragma unroll
      for (int n = 0; n < 4; ++n) {
        accg[m][n] = __builtin_amdgcn_mfma_f32_16x16x32_bf16(af[m], bgf[n], accg[m][n], 0, 0, 0);
        accu[m][n] = __builtin_amdgcn_mfma_f32_16x16x32_bf16(af[m], buf_[n], accu[m][n], 0, 0, 0);
      }
    __builtin_amdgcn_sched_barrier(0);
    __builtin_amdgcn_s_barrier();
  }
#undef STG1

  const int rhi = lane >> 4, clo = lane & 15;
#pragma unroll
  for (int m = 0; m < 2; ++m) {
#pragma unroll
    for (int jj = 0; jj < 4; ++jj) {
      int rloc = wm * 32 + m * 16 + rhi * 4 + jj;
      int row = rowbase + rloc;
      if (row < cnt) {
        unsigned short* ar = g_a + ((size_t)e * TT + row) * II;
#pragma unroll
        for (int n = 0; n < 4; ++n) {
          int i = cb * 128 + wc * 64 + n * 16 + clo;
          float gv = accg[m][n][jj];
          float uv = accu[m][n][jj];
          float av = gv / (1.f + __expf(-gv)) * uv;
          ar[i] = f2bf(av);
        }
      }
    }
  }
}

// GEMM2: 64-row x 128-hcol tile, K=768, double-buffered; atomicAdd combine.
__global__ __launch_bounds__(256) void k_gemm2(float* __restrict__ out) {
  const int tile = blockIdx.x;
  if (tile >= g_ntiles) return;
  const int e = g_tile_e[tile];
  const int rowbase = g_tile_row[tile];
  const int cnt = g_cnt[e];
  const int cb = blockIdx.y;          // 0..7
  const int tid = threadIdx.x;
  const int lane = tid & 63;
  const int wid = tid >> 6;
  const int wm = wid >> 1;
  const int wc = wid & 1;

  __shared__ uint4 sA[2][256];
  __shared__ uint4 sB[2][512];
  __shared__ int s_tok[64];
  __shared__ float s_w[64];

  if (tid < 64) {
    int row = rowbase + tid;
    bool v = row < cnt;
    s_tok[tid] = v ? g_perm_tok[e * TT + row] : 0;
    s_w[tid] = v ? g_perm_w[e * TT + row] : 0.f;
  }

  const int r16 = tid & 15;
  const int c8 = (tid >> 4) & 3;
  const unsigned short* ab = g_a + (size_t)e * TT * II;
  const unsigned short* aptr = ab + (size_t)(rowbase + ((tid >> 6) << 4) + r16) * II + c8 * 8;
  const unsigned short* w2b = g_w2_bf + (size_t)e * HH * II;
  const int h0 = cb * 128 + ((tid >> 6) << 4) + r16;
  const int h1 = cb * 128 + (4 + (tid >> 6)) * 16 + r16;
  const unsigned short* bp0 = w2b + (size_t)h0 * II + c8 * 8;
  const unsigned short* bp1 = w2b + (size_t)h1 * II + c8 * 8;

  const int aoff  = __builtin_amdgcn_readfirstlane(wid * 64 * 16);
  const int boff1 = __builtin_amdgcn_readfirstlane((256 + wid * 64) * 16);

#define STG2(buf, kk) do { \
    gload16(aptr + (kk), (char*)(&sA[buf][0]) + aoff); \
    gload16(bp0 + (kk), (char*)(&sB[buf][0]) + aoff); \
    gload16(bp1 + (kk), (char*)(&sB[buf][0]) + boff1); \
  } while (0)

  f32x4 acc[2][4];
#pragma unroll
  for (int m = 0; m < 2; ++m)
#pragma unroll
    for (int n = 0; n < 4; ++n) acc[m][n] = (f32x4){0.f, 0.f, 0.f, 0.f};

  STG2(0, 0);
  for (int ks = 0; ks < 24; ++ks) {
    const int cur = ks & 1;
    if (ks < 23) {
      STG2(cur ^ 1, (ks + 1) * 32);
      asm volatile("s_waitcnt vmcnt(3)" ::: "memory");
    } else {
      asm volatile("s_waitcnt vmcnt(0)" ::: "memory");
    }
    __builtin_amdgcn_s_barrier();
    __builtin_amdgcn_sched_barrier(0);
    bf16x8 af[2], bfr[4];
#pragma unroll
    for (int m = 0; m < 2; ++m)
      af[m] = *(const bf16x8*)((const char*)(&sA[cur][0]) + (wm * 2 + m) * 1024 + lane * 16);
#pragma unroll
    for (int n = 0; n < 4; ++n)
      bfr[n] = *(const bf16x8*)((const char*)(&sB[cur][0]) + (wc * 4 + n) * 1024 + lane * 16);
#pragma unroll
    for (int m = 0; m < 2; ++m)
#pragma unroll
      for (int n = 0; n < 4; ++n)
        acc[m][n] = __builtin_amdgcn_mfma_f32_16x16x32_bf16(af[m], bfr[n], acc[m][n], 0, 0, 0);
    __builtin_amdgcn_sched_barrier(0);
    __builtin_amdgcn_s_barrier();
  }
#undef STG2

  const int rhi = lane >> 4, clo = lane & 15;
#pragma unroll
  for (int m = 0; m < 2; ++m) {
#pragma unroll
    for (int jj = 0; jj < 4; ++jj) {
      int rloc = wm * 32 + m * 16 + rhi * 4 + jj;
      if (rowbase + rloc < cnt) {
        int tok = s_tok[rloc];
        float w = s_w[rloc];
        float* orow = out + (size_t)tok * HH;
#pragma unroll
        for (int n = 0; n < 4; ++n) {
          int h = cb * 128 + wc * 64 + n * 16 + clo;
          atomicAdd(orow + h, w * acc[m][n][jj]);
        }
      }
    }
  }
}

extern "C" void kernel_launch(void* const* d_in, const int* in_sizes, int n_in,
                              void* d_out, int out_size, void* d_ws, size_t ws_size,
                              hipStream_t stream) {
  (void)in_sizes; (void)n_in; (void)d_ws; (void)ws_size; (void)out_size;
  const float* x   = (const float*)d_in[0];
  const float* gw  = (const float*)d_in[1];
  const float* w13 = (const float*)d_in[2];
  const float* w2  = (const float*)d_in[3];
  float* out = (float*)d_out;

  k_zero<<<dim3(1), dim3(64), 0, stream>>>();
  k_cvt<<<dim3(2048), dim3(256), 0, stream>>>(w13, EE * TWOI * HH, 1);
  k_cvt<<<dim3(2048), dim3(256), 0, stream>>>(w2, EE * HH * II, 2);
  k_router<<<dim3(TT / 4), dim3(256), 0, stream>>>(x, gw);
  k_prefix<<<dim3(1), dim3(64), 0, stream>>>();
  hipMemsetAsync(d_out, 0, (size_t)TT * HH * sizeof(float), stream);
  k_gemm1<<<dim3(MAXTILES, 6), dim3(256), 0, stream>>>();
  k_gemm2<<<dim3(MAXTILES, 8), dim3(256), 0, stream>>>(out);
}

// Round 6
// 210.861 us; speedup vs baseline: 2.3460x; 1.1952x over previous
//
#include <hip/hip_runtime.h>
#include <hip/hip_bf16.h>

#define TT 4096
#define HH 1024
#define II 768
#define EE 8
#define TWOI 1536
#define MAXT 72

typedef __attribute__((ext_vector_type(8))) short bf16x8;
typedef __attribute__((ext_vector_type(4))) float f32x4;

// static device scratch
__device__ unsigned short g_x_bf[TT * HH];
__device__ unsigned short g_w13_bf[EE * TWOI * HH];
__device__ unsigned short g_w2_bf[EE * HH * II];
__device__ unsigned short g_a[EE * TT * II];
__device__ int g_perm_tok[EE * TT];
__device__ float g_perm_w[EE * TT];
__device__ int g_cnt[EE];
__device__ int g_tile_e[MAXT];
__device__ int g_tile_row[MAXT];
__device__ int g_ntiles;

__device__ __forceinline__ unsigned short f2bf(float f) {
  union { float f; unsigned u; } v; v.f = f;
  unsigned r = v.u + 0x7fff + ((v.u >> 16) & 1);   // RNE
  return (unsigned short)(r >> 16);
}

__device__ __forceinline__ void gload16(const void* g, void* l) {
  __builtin_amdgcn_global_load_lds(
      (const __attribute__((address_space(1))) void*)g,
      (__attribute__((address_space(3))) void*)l, 16, 0, 0);
}

__global__ void k_zero() {
  if (threadIdx.x < EE) g_cnt[threadIdx.x] = 0;
}

__global__ void k_cvt(const float* __restrict__ in, int n, int which) {
  unsigned short* dst = (which == 1) ? g_w13_bf : g_w2_bf;
  int idx = (blockIdx.x * blockDim.x + threadIdx.x) * 4;
  int stride = gridDim.x * blockDim.x * 4;
  for (; idx < n; idx += stride) {
    float4 v = *(const float4*)(in + idx);
    ushort4 o;
    o.x = f2bf(v.x); o.y = f2bf(v.y); o.z = f2bf(v.z); o.w = f2bf(v.w);
    *(ushort4*)(dst + idx) = o;
  }
}

// one wave per token: f32 logits, softmax, top-2; scatter to expert lists; x->bf16
__global__ __launch_bounds__(256) void k_router(const float* __restrict__ x,
                                                const float* __restrict__ gw) {
  const int lane = threadIdx.x & 63;
  const int wid = threadIdx.x >> 6;
  const int t = blockIdx.x * 4 + wid;

  const float* xr = x + (size_t)t * HH + lane * 16;
  float4 xv0 = *(const float4*)(xr + 0);
  float4 xv1 = *(const float4*)(xr + 4);
  float4 xv2 = *(const float4*)(xr + 8);
  float4 xv3 = *(const float4*)(xr + 12);

  unsigned short* xd = g_x_bf + (size_t)t * HH + lane * 16;
  ushort4 o0, o1, o2, o3;
  o0.x = f2bf(xv0.x); o0.y = f2bf(xv0.y); o0.z = f2bf(xv0.z); o0.w = f2bf(xv0.w);
  o1.x = f2bf(xv1.x); o1.y = f2bf(xv1.y); o1.z = f2bf(xv1.z); o1.w = f2bf(xv1.w);
  o2.x = f2bf(xv2.x); o2.y = f2bf(xv2.y); o2.z = f2bf(xv2.z); o2.w = f2bf(xv2.w);
  o3.x = f2bf(xv3.x); o3.y = f2bf(xv3.y); o3.z = f2bf(xv3.z); o3.w = f2bf(xv3.w);
  *(ushort4*)(xd + 0) = o0;
  *(ushort4*)(xd + 4) = o1;
  *(ushort4*)(xd + 8) = o2;
  *(ushort4*)(xd + 12) = o3;

  float lg[EE];
#pragma unroll
  for (int ei = 0; ei < EE; ++ei) {
    const float* gr = gw + ei * HH + lane * 16;
    float4 g0 = *(const float4*)(gr + 0);
    float4 g1 = *(const float4*)(gr + 4);
    float4 g2 = *(const float4*)(gr + 8);
    float4 g3 = *(const float4*)(gr + 12);
    float a = xv0.x * g0.x + xv0.y * g0.y + xv0.z * g0.z + xv0.w * g0.w
            + xv1.x * g1.x + xv1.y * g1.y + xv1.z * g1.z + xv1.w * g1.w
            + xv2.x * g2.x + xv2.y * g2.y + xv2.z * g2.z + xv2.w * g2.w
            + xv3.x * g3.x + xv3.y * g3.y + xv3.z * g3.z + xv3.w * g3.w;
#pragma unroll
    for (int s = 32; s > 0; s >>= 1) a += __shfl_xor(a, s);
    lg[ei] = a;
  }

  if (lane == 0) {
    float mx = lg[0];
#pragma unroll
    for (int ei = 1; ei < EE; ++ei) mx = fmaxf(mx, lg[ei]);
    float p[EE]; float s = 0.f;
#pragma unroll
    for (int ei = 0; ei < EE; ++ei) { p[ei] = expf(lg[ei] - mx); s += p[ei]; }
    float inv = 1.f / s;
    int e1 = 0; float b1 = lg[0];
#pragma unroll
    for (int ei = 1; ei < EE; ++ei) if (lg[ei] > b1) { b1 = lg[ei]; e1 = ei; }
    int e2 = -1; float b2 = -3.0e38f;
#pragma unroll
    for (int ei = 0; ei < EE; ++ei)
      if (ei != e1 && lg[ei] > b2) { b2 = lg[ei]; e2 = ei; }

    int p1 = atomicAdd(&g_cnt[e1], 1);
    g_perm_tok[e1 * TT + p1] = t;
    g_perm_w[e1 * TT + p1] = p[e1] * inv;
    int p2 = atomicAdd(&g_cnt[e2], 1);
    g_perm_tok[e2 * TT + p2] = t;
    g_perm_w[e2 * TT + p2] = p[e2] * inv;
  }
}

// build compact tile list: tile -> (expert, rowbase), 128-row tiles
__global__ void k_prefix() {
  if (threadIdx.x == 0) {
    int t = 0;
    for (int e = 0; e < EE; ++e) {
      int c = g_cnt[e];
      for (int rb = 0; rb < c; rb += 128) {
        g_tile_e[t] = e;
        g_tile_row[t] = rb;
        ++t;
      }
    }
    g_ntiles = t;
  }
}

// GEMM1: 128-row x 128-icol tile, g+u, 8 waves, double-buffered LDS, counted vmcnt.
// Fragment-ordered LDS: 1KB chunk = 16(row)x32(k) fragment; granule in chunk = c8*16+r16.
__global__ __launch_bounds__(512) void k_gemm1() {
  const int tile = blockIdx.x;
  if (tile >= g_ntiles) return;
  const int e = g_tile_e[tile];
  const int rowbase = g_tile_row[tile];
  const int cnt = g_cnt[e];
  const int cb = blockIdx.y;          // 0..5
  const int tid = threadIdx.x;
  const int lane = tid & 63;
  const int wid = tid >> 6;           // 0..7
  const int wm = wid >> 1;            // row quarter (32 rows)
  const int wc = wid & 1;             // col half (64 cols)

  __shared__ uint4 sA[2][512];        // 8KB per buf: 8 chunks of 16rows x 32k
  __shared__ uint4 sBg[2][512];
  __shared__ uint4 sBu[2][512];

  const int r16 = tid & 15;
  const int c8 = (tid >> 4) & 3;
  const int rb = tid >> 6;            // chunk 0..7
  const int arow = rowbase + rb * 16 + r16;
  const int tok = (arow < cnt) ? g_perm_tok[e * TT + arow] : 0;
  const unsigned short* aptr = g_x_bf + (size_t)tok * HH + c8 * 8;
  const unsigned short* w13b = g_w13_bf + (size_t)e * TWOI * HH;
  const int j = cb * 128 + rb * 16 + r16;
  const unsigned short* bgp = w13b + (size_t)j * HH + c8 * 8;
  const unsigned short* bup = bgp + (size_t)II * HH;

  const int soff = __builtin_amdgcn_readfirstlane(wid * 64 * 16);

#define STG1(buf, kk) do { \
    gload16(aptr + (kk), (char*)(&sA[buf][0]) + soff); \
    gload16(bgp + (kk), (char*)(&sBg[buf][0]) + soff); \
    gload16(bup + (kk), (char*)(&sBu[buf][0]) + soff); \
  } while (0)

  f32x4 accg[2][4], accu[2][4];
#pragma unroll
  for (int m = 0; m < 2; ++m)
#pragma unroll
    for (int n = 0; n < 4; ++n) {
      accg[m][n] = (f32x4){0.f, 0.f, 0.f, 0.f};
      accu[m][n] = (f32x4){0.f, 0.f, 0.f, 0.f};
    }

  STG1(0, 0);
  for (int ks = 0; ks < 32; ++ks) {
    const int cur = ks & 1;
    if (ks < 31) {
      STG1(cur ^ 1, (ks + 1) * 32);
      asm volatile("s_waitcnt vmcnt(3)" ::: "memory");
    } else {
      asm volatile("s_waitcnt vmcnt(0)" ::: "memory");
    }
    __builtin_amdgcn_s_barrier();
    __builtin_amdgcn_sched_barrier(0);
    bf16x8 af[2], bgf[4], buf_[4];
#pragma unroll
    for (int m = 0; m < 2; ++m)
      af[m] = *(const bf16x8*)((const char*)(&sA[cur][0]) + (wm * 2 + m) * 1024 + lane * 16);
#pragma unroll
    for (int n = 0; n < 4; ++n) {
      int jb = wc * 4 + n;
      bgf[n] = *(const bf16x8*)((const char*)(&sBg[cur][0]) + jb * 1024 + lane * 16);
      buf_[n] = *(const bf16x8*)((const char*)(&sBu[cur][0]) + jb * 1024 + lane * 16);
    }
#pragma unroll
    for (int m = 0; m < 2; ++m)
#pragma unroll
      for (int n = 0; n < 4; ++n) {
        accg[m][n] = __builtin_amdgcn_mfma_f32_16x16x32_bf16(af[m], bgf[n], accg[m][n], 0, 0, 0);
        accu[m][n] = __builtin_amdgcn_mfma_f32_16x16x32_bf16(af[m], buf_[n], accu[m][n], 0, 0, 0);
      }
    __builtin_amdgcn_sched_barrier(0);
    __builtin_amdgcn_s_barrier();
  }
#undef STG1

  const int rhi = lane >> 4, clo = lane & 15;
#pragma unroll
  for (int m = 0; m < 2; ++m) {
#pragma unroll
    for (int jj = 0; jj < 4; ++jj) {
      int rloc = wm * 32 + m * 16 + rhi * 4 + jj;
      int row = rowbase + rloc;
      if (row < cnt) {
        unsigned short* ar = g_a + ((size_t)e * TT + row) * II;
#pragma unroll
        for (int n = 0; n < 4; ++n) {
          int i = cb * 128 + wc * 64 + n * 16 + clo;
          float gv = accg[m][n][jj];
          float uv = accu[m][n][jj];
          float av = gv / (1.f + __expf(-gv)) * uv;
          ar[i] = f2bf(av);
        }
      }
    }
  }
}

// GEMM2: 128-row x 128-hcol tile, K=768, 8 waves, double-buffered; atomicAdd combine.
__global__ __launch_bounds__(512) void k_gemm2(float* __restrict__ out) {
  const int tile = blockIdx.x;
  if (tile >= g_ntiles) return;
  const int e = g_tile_e[tile];
  const int rowbase = g_tile_row[tile];
  const int cnt = g_cnt[e];
  const int cb = blockIdx.y;          // 0..7
  const int tid = threadIdx.x;
  const int lane = tid & 63;
  const int wid = tid >> 6;
  const int wm = wid >> 1;
  const int wc = wid & 1;

  __shared__ uint4 sA[2][512];
  __shared__ uint4 sB[2][512];
  __shared__ int s_tok[128];
  __shared__ float s_w[128];

  if (tid < 128) {
    int row = rowbase + tid;
    bool v = row < cnt;
    s_tok[tid] = v ? g_perm_tok[e * TT + row] : 0;
    s_w[tid] = v ? g_perm_w[e * TT + row] : 0.f;
  }

  const int r16 = tid & 15;
  const int c8 = (tid >> 4) & 3;
  const int rb = tid >> 6;
  const unsigned short* ab = g_a + (size_t)e * TT * II;
  const unsigned short* aptr = ab + (size_t)(rowbase + rb * 16 + r16) * II + c8 * 8;
  const unsigned short* w2b = g_w2_bf + (size_t)e * HH * II;
  const int h = cb * 128 + rb * 16 + r16;
  const unsigned short* bp = w2b + (size_t)h * II + c8 * 8;

  const int soff = __builtin_amdgcn_readfirstlane(wid * 64 * 16);

#define STG2(buf, kk) do { \
    gload16(aptr + (kk), (char*)(&sA[buf][0]) + soff); \
    gload16(bp + (kk), (char*)(&sB[buf][0]) + soff); \
  } while (0)

  f32x4 acc[2][4];
#pragma unroll
  for (int m = 0; m < 2; ++m)
#pragma unroll
    for (int n = 0; n < 4; ++n) acc[m][n] = (f32x4){0.f, 0.f, 0.f, 0.f};

  STG2(0, 0);
  for (int ks = 0; ks < 24; ++ks) {
    const int cur = ks & 1;
    if (ks < 23) {
      STG2(cur ^ 1, (ks + 1) * 32);
      asm volatile("s_waitcnt vmcnt(2)" ::: "memory");
    } else {
      asm volatile("s_waitcnt vmcnt(0)" ::: "memory");
    }
    __builtin_amdgcn_s_barrier();
    __builtin_amdgcn_sched_barrier(0);
    bf16x8 af[2], bfr[4];
#pragma unroll
    for (int m = 0; m < 2; ++m)
      af[m] = *(const bf16x8*)((const char*)(&sA[cur][0]) + (wm * 2 + m) * 1024 + lane * 16);
#pragma unroll
    for (int n = 0; n < 4; ++n)
      bfr[n] = *(const bf16x8*)((const char*)(&sB[cur][0]) + (wc * 4 + n) * 1024 + lane * 16);
#pragma unroll
    for (int m = 0; m < 2; ++m)
#pragma unroll
      for (int n = 0; n < 4; ++n)
        acc[m][n] = __builtin_amdgcn_mfma_f32_16x16x32_bf16(af[m], bfr[n], acc[m][n], 0, 0, 0);
    __builtin_amdgcn_sched_barrier(0);
    __builtin_amdgcn_s_barrier();
  }
#undef STG2

  const int rhi = lane >> 4, clo = lane & 15;
#pragma unroll
  for (int m = 0; m < 2; ++m) {
#pragma unroll
    for (int jj = 0; jj < 4; ++jj) {
      int rloc = wm * 32 + m * 16 + rhi * 4 + jj;
      if (rowbase + rloc < cnt) {
        int tok = s_tok[rloc];
        float w = s_w[rloc];
        float* orow = out + (size_t)tok * HH;
#pragma unroll
        for (int n = 0; n < 4; ++n) {
          int h2 = cb * 128 + wc * 64 + n * 16 + clo;
          atomicAdd(orow + h2, w * acc[m][n][jj]);
        }
      }
    }
  }
}

extern "C" void kernel_launch(void* const* d_in, const int* in_sizes, int n_in,
                              void* d_out, int out_size, void* d_ws, size_t ws_size,
                              hipStream_t stream) {
  (void)in_sizes; (void)n_in; (void)d_ws; (void)ws_size; (void)out_size;
  const float* x   = (const float*)d_in[0];
  const float* gw  = (const float*)d_in[1];
  const float* w13 = (const float*)d_in[2];
  const float* w2  = (const float*)d_in[3];
  float* out = (float*)d_out;

  k_zero<<<dim3(1), dim3(64), 0, stream>>>();
  k_cvt<<<dim3(2048), dim3(256), 0, stream>>>(w13, EE * TWOI * HH, 1);
  k_cvt<<<dim3(2048), dim3(256), 0, stream>>>(w2, EE * HH * II, 2);
  k_router<<<dim3(TT / 4), dim3(256), 0, stream>>>(x, gw);
  k_prefix<<<dim3(1), dim3(64), 0, stream>>>();
  hipMemsetAsync(d_out, 0, (size_t)TT * HH * sizeof(float), stream);
  k_gemm1<<<dim3(MAXT, 6), dim3(512), 0, stream>>>();
  k_gemm2<<<dim3(MAXT, 8), dim3(512), 0, stream>>>(out);
}